// Round 1
// baseline (548.029 us; speedup 1.0000x reference)
//
#include <hip/hip_runtime.h>

#define RES 64
#define NP 20

// per pixel: values (f0,f1,m,d0,d1) at location (fi,fj)
// accumulators: sa=Σa, sai=Σa*i, saj=Σa*j, A=Σg1*d0, B=Σg0*d0, C=Σg1*d1, D=Σg0*d1
// where a=|m|, g0=a*m*f0, g1=a*m*f1
__device__ __forceinline__ void accum_pixel(float f0, float f1, float m, float d0, float d1,
                                            float fi, float fj,
                                            float& sa, float& sai, float& saj,
                                            float& A, float& B, float& C, float& D) {
    float a  = fabsf(m);
    float w  = a * m;
    float g0 = w * f0;
    float g1 = w * f1;
    sa  += a;
    sai  = fmaf(a, fi, sai);
    saj  = fmaf(a, fj, saj);
    A    = fmaf(g1, d0, A);
    B    = fmaf(g0, d0, B);
    C    = fmaf(g1, d1, C);
    D    = fmaf(g0, d1, D);
}

// One block (256 threads) per (b,p) plane of 64x64 pixels x 5 channels.
// Each thread handles 16 pixels: 4 iterations x 4 consecutive pixels,
// loading 4 pixels (20 floats) as 5 aligned float4's per iteration.
__global__ __launch_bounds__(256) void reduce_kernel(const float* __restrict__ x,
                                                     float* __restrict__ ws) {
    const int bp  = blockIdx.x;
    const int tid = threadIdx.x;
    const float* base = x + (size_t)bp * (RES * RES * 5);

    float sa = 0.f, sai = 0.f, saj = 0.f;
    float A = 0.f, B = 0.f, C = 0.f, D = 0.f;

    // pixel index = k*1024 + tid*4 + s ;  i = pix>>6, j = pix&63
    // j = (tid*4)&63 + s  (no wrap since (tid*4)%64 <= 60, s <= 3)
    // i = k*16 + (tid>>4)
    const float j0 = (float)((tid * 4) & 63);
    const float i0 = (float)(tid >> 4);

    #pragma unroll
    for (int k = 0; k < 4; ++k) {
        const float4* p4 = (const float4*)(base + (size_t)(k * 1024 + tid * 4) * 5);
        float4 v0 = p4[0];
        float4 v1 = p4[1];
        float4 v2 = p4[2];
        float4 v3 = p4[3];
        float4 v4 = p4[4];
        float fi = i0 + (float)(16 * k);

        // pixel 0: f0=v0.x f1=v0.y m=v0.z d0=v0.w d1=v1.x
        accum_pixel(v0.x, v0.y, v0.z, v0.w, v1.x, fi, j0 + 0.f, sa, sai, saj, A, B, C, D);
        // pixel 1: f0=v1.y f1=v1.z m=v1.w d0=v2.x d1=v2.y
        accum_pixel(v1.y, v1.z, v1.w, v2.x, v2.y, fi, j0 + 1.f, sa, sai, saj, A, B, C, D);
        // pixel 2: f0=v2.z f1=v2.w m=v3.x d0=v3.y d1=v3.z
        accum_pixel(v2.z, v2.w, v3.x, v3.y, v3.z, fi, j0 + 2.f, sa, sai, saj, A, B, C, D);
        // pixel 3: f0=v3.w f1=v4.x m=v4.y d0=v4.z d1=v4.w
        accum_pixel(v3.w, v4.x, v4.y, v4.z, v4.w, fi, j0 + 3.f, sa, sai, saj, A, B, C, D);
    }

    // wave(64) butterfly reduce of the 7 accumulators
    #pragma unroll
    for (int off = 32; off > 0; off >>= 1) {
        sa  += __shfl_down(sa,  off);
        sai += __shfl_down(sai, off);
        saj += __shfl_down(saj, off);
        A   += __shfl_down(A,   off);
        B   += __shfl_down(B,   off);
        C   += __shfl_down(C,   off);
        D   += __shfl_down(D,   off);
    }

    __shared__ float red[4][7];
    const int wid  = tid >> 6;
    const int lane = tid & 63;
    if (lane == 0) {
        red[wid][0] = sa;  red[wid][1] = sai; red[wid][2] = saj;
        red[wid][3] = A;   red[wid][4] = B;   red[wid][5] = C;  red[wid][6] = D;
    }
    __syncthreads();

    if (tid == 0) {
        float t[7];
        #pragma unroll
        for (int q = 0; q < 7; ++q)
            t[q] = red[0][q] + red[1][q] + red[2][q] + red[3][q];
        float denom = t[0];
        float ds    = (denom == 0.f) ? 1.f : denom;
        float vfx = (t[3] + t[1]) / ds;   // ( A + sai) / ds
        float vfy = (t[2] - t[4]) / ds;   // (saj -  B) / ds
        float vsx = (t[1] - t[5]) / ds;   // (sai -  C) / ds
        float vsy = (t[6] + t[2]) / ds;   // ( D + saj) / ds
        float* w = ws + (size_t)bp * 5;
        w[0] = denom; w[1] = vfx; w[2] = vfy; w[3] = vsx; w[4] = vsy;
    }
}

// One thread per output element: out[b][r][c], r in [0,21), c in {0,1}
__global__ __launch_bounds__(256) void combine_kernel(const float* __restrict__ ws,
                                                      float* __restrict__ out, int B) {
    int gid = blockIdx.x * blockDim.x + threadIdx.x;
    if (gid >= B * 42) return;
    int c = gid & 1;
    int t = gid >> 1;        // b*21 + r
    int r = t % 21;
    int b = t / 21;
    const float* w = ws + (size_t)b * NP * 5;
    float val;
    if (r == 0) {
        // kp0 = sum over roots p=0,4,8,12,16 of (denom!=0 ? vf[p] : 0) / 5
        float s = 0.f;
        #pragma unroll
        for (int f = 0; f < 5; ++f) {
            int p = 4 * f;
            float denom = w[p * 5];
            float vf    = w[p * 5 + 1 + c];
            s += (denom != 0.f) ? vf : 0.f;
        }
        val = s / 5.0f;
    } else {
        int q  = r;                 // 1..20
        int iq = (q - 1) >> 2;
        int jq = 4 * iq + 4 - q;
        int pq = 4 * iq + jq;
        int pn = pq + 1; if (pn > NP - 1) pn = NP - 1;
        float vs = w[pq * 5 + 3 + c];
        if (jq == 3) {
            val = vs;               // tip
        } else {
            float vf = w[pn * 5 + 1 + c];
            val = (vs + vf) * 0.5f;
        }
    }
    out[gid] = val;
}

extern "C" void kernel_launch(void* const* d_in, const int* in_sizes, int n_in,
                              void* d_out, int out_size, void* d_ws, size_t ws_size,
                              hipStream_t stream) {
    const float* x = (const float*)d_in[0];
    float* out = (float*)d_out;
    float* ws  = (float*)d_ws;      // needs B*20*5*4 = 102,400 bytes

    int n  = in_sizes[0];
    int BP = n / (RES * RES * 5);   // B * N_PHAL
    int B  = BP / NP;

    reduce_kernel<<<BP, 256, 0, stream>>>(x, ws);

    int total  = B * 42;
    int blocks = (total + 255) / 256;
    combine_kernel<<<blocks, 256, 0, stream>>>(ws, out, B);
}

// Round 2
// 535.916 us; speedup vs baseline: 1.0226x; 1.0226x over previous
//
#include <hip/hip_runtime.h>

#define RES 64
#define NP 20
#define CHUNK_F4 1280   // float4s per staged chunk = 20 KB = 1024 pixels (16 rows)
#define NCHUNK 4

// per pixel: values (f0,f1,m,d0,d1) at location (fi,fj)
// accumulators: sa=Σa, sai=Σa*i, saj=Σa*j, A=Σg1*d0, B=Σg0*d0, C=Σg1*d1, D=Σg0*d1
// where a=|m|, g0=a*m*f0, g1=a*m*f1
__device__ __forceinline__ void accum_pixel(float f0, float f1, float m, float d0, float d1,
                                            float fi, float fj,
                                            float& sa, float& sai, float& saj,
                                            float& A, float& B, float& C, float& D) {
    float a  = fabsf(m);
    float w  = a * m;
    float g0 = w * f0;
    float g1 = w * f1;
    sa  += a;
    sai  = fmaf(a, fi, sai);
    saj  = fmaf(a, fj, saj);
    A    = fmaf(g1, d0, A);
    B    = fmaf(g0, d0, B);
    C    = fmaf(g1, d1, C);
    D    = fmaf(g0, d1, D);
}

// async global->LDS, 16 B per lane; LDS dest = wave-uniform base + lane*16
__device__ __forceinline__ void load_lds16(const float4* g, float4* l) {
    __builtin_amdgcn_global_load_lds(
        (const __attribute__((address_space(1))) void*)g,
        (__attribute__((address_space(3))) void*)l,
        16, 0, 0);
}

// One block (256 threads) per (b,p) plane (64x64 pixels x 5 floats = 80 KB).
// Stage 20 KB chunks into LDS with perfectly-coalesced global_load_lds,
// then each thread consumes 4 consecutive pixels (20 floats) per chunk.
__global__ __launch_bounds__(256) void reduce_kernel(const float* __restrict__ x,
                                                     float* __restrict__ ws) {
    __shared__ float4 buf[CHUNK_F4];   // 20 KB -> 8 blocks/CU
    const int bp   = blockIdx.x;
    const int tid  = threadIdx.x;
    const int w    = tid >> 6;
    const int lane = tid & 63;
    const float4* plane = (const float4*)(x + (size_t)bp * (RES * RES * 5));

    float sa = 0.f, sai = 0.f, saj = 0.f;
    float A = 0.f, B = 0.f, C = 0.f, D = 0.f;

    // pixel index within chunk = tid*4 + s ; col = (tid*4)&63 + s, row = tid>>4
    const float j0 = (float)((tid * 4) & 63);
    const float i0 = (float)(tid >> 4);

    for (int k = 0; k < NCHUNK; ++k) {
        // stage chunk k: wave w loads float4s [w*320 + v*64 + lane], v=0..4
        const int wbase = w * 320;
        const float4* gsrc = plane + (size_t)k * CHUNK_F4 + wbase + lane;
        #pragma unroll
        for (int v = 0; v < 5; ++v) {
            load_lds16(gsrc + v * 64, &buf[wbase + v * 64]);
        }
        __syncthreads();   // drains vmcnt(0) then barriers: LDS chunk ready

        const float* bf = (const float*)buf;
        const float* my = bf + tid * 20;          // byte offset tid*80, 16B-aligned
        float4 v0 = *(const float4*)(my + 0);
        float4 v1 = *(const float4*)(my + 4);
        float4 v2 = *(const float4*)(my + 8);
        float4 v3 = *(const float4*)(my + 12);
        float4 v4 = *(const float4*)(my + 16);
        float fi = i0 + (float)(16 * k);

        // pixel 0: f0=v0.x f1=v0.y m=v0.z d0=v0.w d1=v1.x
        accum_pixel(v0.x, v0.y, v0.z, v0.w, v1.x, fi, j0 + 0.f, sa, sai, saj, A, B, C, D);
        // pixel 1
        accum_pixel(v1.y, v1.z, v1.w, v2.x, v2.y, fi, j0 + 1.f, sa, sai, saj, A, B, C, D);
        // pixel 2
        accum_pixel(v2.z, v2.w, v3.x, v3.y, v3.z, fi, j0 + 2.f, sa, sai, saj, A, B, C, D);
        // pixel 3
        accum_pixel(v3.w, v4.x, v4.y, v4.z, v4.w, fi, j0 + 3.f, sa, sai, saj, A, B, C, D);

        __syncthreads();   // everyone done reading before next chunk overwrites
    }

    // wave(64) butterfly reduce of the 7 accumulators
    #pragma unroll
    for (int off = 32; off > 0; off >>= 1) {
        sa  += __shfl_down(sa,  off);
        sai += __shfl_down(sai, off);
        saj += __shfl_down(saj, off);
        A   += __shfl_down(A,   off);
        B   += __shfl_down(B,   off);
        C   += __shfl_down(C,   off);
        D   += __shfl_down(D,   off);
    }

    // cross-wave reduce via (now free) staging buffer
    float* red = (float*)buf;
    if (lane == 0) {
        red[w * 8 + 0] = sa;  red[w * 8 + 1] = sai; red[w * 8 + 2] = saj;
        red[w * 8 + 3] = A;   red[w * 8 + 4] = B;   red[w * 8 + 5] = C;
        red[w * 8 + 6] = D;
    }
    __syncthreads();

    if (tid == 0) {
        float t[7];
        #pragma unroll
        for (int q = 0; q < 7; ++q)
            t[q] = red[q] + red[8 + q] + red[16 + q] + red[24 + q];
        float denom = t[0];
        float ds    = (denom == 0.f) ? 1.f : denom;
        float vfx = (t[3] + t[1]) / ds;   // ( A + sai) / ds
        float vfy = (t[2] - t[4]) / ds;   // (saj -  B) / ds
        float vsx = (t[1] - t[5]) / ds;   // (sai -  C) / ds
        float vsy = (t[6] + t[2]) / ds;   // ( D + saj) / ds
        float* o = ws + (size_t)bp * 5;
        o[0] = denom; o[1] = vfx; o[2] = vfy; o[3] = vsx; o[4] = vsy;
    }
}

// One thread per output element: out[b][r][c], r in [0,21), c in {0,1}
__global__ __launch_bounds__(256) void combine_kernel(const float* __restrict__ ws,
                                                      float* __restrict__ out, int B) {
    int gid = blockIdx.x * blockDim.x + threadIdx.x;
    if (gid >= B * 42) return;
    int c = gid & 1;
    int t = gid >> 1;        // b*21 + r
    int r = t % 21;
    int b = t / 21;
    const float* w = ws + (size_t)b * NP * 5;
    float val;
    if (r == 0) {
        float s = 0.f;
        #pragma unroll
        for (int f = 0; f < 5; ++f) {
            int p = 4 * f;
            float denom = w[p * 5];
            float vf    = w[p * 5 + 1 + c];
            s += (denom != 0.f) ? vf : 0.f;
        }
        val = s / 5.0f;
    } else {
        int q  = r;                 // 1..20
        int iq = (q - 1) >> 2;
        int jq = 4 * iq + 4 - q;
        int pq = 4 * iq + jq;
        int pn = pq + 1; if (pn > NP - 1) pn = NP - 1;
        float vs = w[pq * 5 + 3 + c];
        if (jq == 3) {
            val = vs;               // tip
        } else {
            float vf = w[pn * 5 + 1 + c];
            val = (vs + vf) * 0.5f;
        }
    }
    out[gid] = val;
}

extern "C" void kernel_launch(void* const* d_in, const int* in_sizes, int n_in,
                              void* d_out, int out_size, void* d_ws, size_t ws_size,
                              hipStream_t stream) {
    const float* x = (const float*)d_in[0];
    float* out = (float*)d_out;
    float* ws  = (float*)d_ws;      // needs B*20*5*4 = 102,400 bytes

    int n  = in_sizes[0];
    int BP = n / (RES * RES * 5);   // B * N_PHAL
    int B  = BP / NP;

    reduce_kernel<<<BP, 256, 0, stream>>>(x, ws);

    int total  = B * 42;
    int blocks = (total + 255) / 256;
    combine_kernel<<<blocks, 256, 0, stream>>>(ws, out, B);
}

// Round 4
// 533.955 us; speedup vs baseline: 1.0264x; 1.0037x over previous
//
#include <hip/hip_runtime.h>

#define RES 64
#define NP 20
#define CHUNK_F4 1280   // float4s per staged chunk = 20 KB = 1024 pixels (16 rows)
#define NCHUNK 4

// per pixel: values (f0,f1,m,d0,d1) at location (fi,fj)
// accumulators: sa=Σa, sai=Σa*i, saj=Σa*j, A=Σg1*d0, B=Σg0*d0, C=Σg1*d1, D=Σg0*d1
// where a=|m|, g0=a*m*f0, g1=a*m*f1
__device__ __forceinline__ void accum_pixel(float f0, float f1, float m, float d0, float d1,
                                            float fi, float fj,
                                            float& sa, float& sai, float& saj,
                                            float& A, float& B, float& C, float& D) {
    float a  = fabsf(m);
    float w  = a * m;
    float g0 = w * f0;
    float g1 = w * f1;
    sa  += a;
    sai  = fmaf(a, fi, sai);
    saj  = fmaf(a, fj, saj);
    A    = fmaf(g1, d0, A);
    B    = fmaf(g0, d0, B);
    C    = fmaf(g1, d1, C);
    D    = fmaf(g0, d1, D);
}

// async global->LDS, 16 B per lane; LDS dest = wave-uniform base + lane*16
__device__ __forceinline__ void load_lds16(const float4* g, float4* l) {
    __builtin_amdgcn_global_load_lds(
        (const __attribute__((address_space(1))) void*)g,
        (__attribute__((address_space(3))) void*)l,
        16, 0, 0);
}

// One block (256 threads) per (b,p) plane (64x64 px x 5 floats = 80 KB).
// Double-buffered 20 KB chunks via global_load_lds. KEY: wave w stages
// float4s [320w, 320w+320) and its lanes consume exactly that range
// (thread tid reads float4s [tid*5, tid*5+5) = [320w+5*lane, ...)), so the
// chunk loop is wave-private: NO barriers, per-wave counted vmcnt only.
__global__ __launch_bounds__(256) void reduce_kernel(const float* __restrict__ x,
                                                     float* __restrict__ ws) {
    __shared__ float4 buf[2][CHUNK_F4];   // 40 KB -> 4 blocks/CU (16 waves)
    const int bp   = blockIdx.x;
    const int tid  = threadIdx.x;
    const int w    = tid >> 6;
    const int lane = tid & 63;
    const float4* plane = (const float4*)(x + (size_t)bp * (RES * RES * 5));
    const int wbase = w * 320;

    float sa = 0.f, sai = 0.f, saj = 0.f;
    float A = 0.f, B = 0.f, C = 0.f, D = 0.f;

    const float j0 = (float)((tid * 4) & 63);
    const float i0 = (float)(tid >> 4);

    // prologue: stage chunk 0 -> buf[0] (5 loads outstanding)
    {
        const float4* g = plane + wbase + lane;
        float4* dst = &buf[0][wbase];
        #pragma unroll
        for (int v = 0; v < 5; ++v) load_lds16(g + v * 64, dst + v * 64);
    }

    #pragma unroll
    for (int k = 0; k < NCHUNK; ++k) {
        if (k + 1 < NCHUNK) {
            // ds_reads of chunk k-1 were all consumed; make that explicit
            // before overwriting buf[(k+1)&1] via vmem->LDS writes.
            asm volatile("s_waitcnt lgkmcnt(0)" ::: "memory");
            const float4* g = plane + (size_t)(k + 1) * CHUNK_F4 + wbase + lane;
            float4* dst = &buf[(k + 1) & 1][wbase];
            #pragma unroll
            for (int v = 0; v < 5; ++v) load_lds16(g + v * 64, dst + v * 64);
            // outstanding = 10; wait until chunk k's 5 have landed,
            // keep chunk k+1's 5 in flight (never drain to 0 mid-loop)
            asm volatile("s_waitcnt vmcnt(5)" ::: "memory");
        } else {
            asm volatile("s_waitcnt vmcnt(0)" ::: "memory");
        }

        const float* my = (const float*)buf[k & 1] + tid * 20;  // wave-private
        float4 v0 = *(const float4*)(my + 0);
        float4 v1 = *(const float4*)(my + 4);
        float4 v2 = *(const float4*)(my + 8);
        float4 v3 = *(const float4*)(my + 12);
        float4 v4 = *(const float4*)(my + 16);
        float fi = i0 + (float)(16 * k);

        accum_pixel(v0.x, v0.y, v0.z, v0.w, v1.x, fi, j0 + 0.f, sa, sai, saj, A, B, C, D);
        accum_pixel(v1.y, v1.z, v1.w, v2.x, v2.y, fi, j0 + 1.f, sa, sai, saj, A, B, C, D);
        accum_pixel(v2.z, v2.w, v3.x, v3.y, v3.z, fi, j0 + 2.f, sa, sai, saj, A, B, C, D);
        accum_pixel(v3.w, v4.x, v4.y, v4.z, v4.w, fi, j0 + 3.f, sa, sai, saj, A, B, C, D);
    }

    // wave(64) butterfly reduce of the 7 accumulators
    #pragma unroll
    for (int off = 32; off > 0; off >>= 1) {
        sa  += __shfl_down(sa,  off);
        sai += __shfl_down(sai, off);
        saj += __shfl_down(saj, off);
        A   += __shfl_down(A,   off);
        B   += __shfl_down(B,   off);
        C   += __shfl_down(C,   off);
        D   += __shfl_down(D,   off);
    }

    __syncthreads();           // all waves done reading buf before overlay
    float* red = (float*)buf;
    if (lane == 0) {
        red[w * 8 + 0] = sa;  red[w * 8 + 1] = sai; red[w * 8 + 2] = saj;
        red[w * 8 + 3] = A;   red[w * 8 + 4] = B;   red[w * 8 + 5] = C;
        red[w * 8 + 6] = D;
    }
    __syncthreads();

    if (tid == 0) {
        float t[7];
        #pragma unroll
        for (int q = 0; q < 7; ++q)
            t[q] = red[q] + red[8 + q] + red[16 + q] + red[24 + q];
        float denom = t[0];
        float ds    = (denom == 0.f) ? 1.f : denom;
        float vfx = (t[3] + t[1]) / ds;   // ( A + sai) / ds
        float vfy = (t[2] - t[4]) / ds;   // (saj -  B) / ds
        float vsx = (t[1] - t[5]) / ds;   // (sai -  C) / ds
        float vsy = (t[6] + t[2]) / ds;   // ( D + saj) / ds
        float* o = ws + (size_t)bp * 5;
        o[0] = denom; o[1] = vfx; o[2] = vfy; o[3] = vsx; o[4] = vsy;
    }
}

// One thread per output element: out[b][r][c], r in [0,21), c in {0,1}
__global__ __launch_bounds__(256) void combine_kernel(const float* __restrict__ ws,
                                                      float* __restrict__ out, int B) {
    int gid = blockIdx.x * blockDim.x + threadIdx.x;
    if (gid >= B * 42) return;
    int c = gid & 1;
    int t = gid >> 1;        // b*21 + r
    int r = t % 21;
    int b = t / 21;
    const float* w = ws + (size_t)b * NP * 5;
    float val;
    if (r == 0) {
        float s = 0.f;
        #pragma unroll
        for (int f = 0; f < 5; ++f) {
            int p = 4 * f;
            float denom = w[p * 5];
            float vf    = w[p * 5 + 1 + c];
            s += (denom != 0.f) ? vf : 0.f;
        }
        val = s / 5.0f;
    } else {
        int q  = r;                 // 1..20
        int iq = (q - 1) >> 2;
        int jq = 4 * iq + 4 - q;
        int pq = 4 * iq + jq;
        int pn = pq + 1; if (pn > NP - 1) pn = NP - 1;
        float vs = w[pq * 5 + 3 + c];
        if (jq == 3) {
            val = vs;               // tip
        } else {
            float vf = w[pn * 5 + 1 + c];
            val = (vs + vf) * 0.5f;
        }
    }
    out[gid] = val;
}

extern "C" void kernel_launch(void* const* d_in, const int* in_sizes, int n_in,
                              void* d_out, int out_size, void* d_ws, size_t ws_size,
                              hipStream_t stream) {
    const float* x = (const float*)d_in[0];
    float* out = (float*)d_out;
    float* ws  = (float*)d_ws;      // needs B*20*5*4 = 102,400 bytes

    int n  = in_sizes[0];
    int BP = n / (RES * RES * 5);   // B * N_PHAL
    int B  = BP / NP;

    reduce_kernel<<<BP, 256, 0, stream>>>(x, ws);

    int total  = B * 42;
    int blocks = (total + 255) / 256;
    combine_kernel<<<blocks, 256, 0, stream>>>(ws, out, B);
}